// Round 6
// baseline (92.235 us; speedup 1.0000x reference)
//
#include <hip/hip_runtime.h>

// B=512, L=512, A=20, C=8. All f32.
// Algebra: _row term == 0 (exp(-5000) underflows). One-hot x =>
// (xp+_column)[b,k,p] = U[aa[b,p],k], U = I + V (V from clip(lpm)*pm,
// upper-tri mirrored, diag 0, col 19 never written).
// Linear conv/pool stack => 8x512 matrix W_eff; out[b,k,c] =
//   T[b,c,k] + sum_i T[b,c,i] * V[i,k],  T[b,c,i] = sum_{p: aa[b,p]=i} W_eff[c,p].
//
// W_eff built via impulse responses; impulses stay sparse (support <= 5),
// so each block tracks an 8-wide window per channel. Stored TRANSPOSED
// ([p][c]) so cnn_main's hit threads read 8 taps as 2x ds_read_b128.

// ---------------- Kernel 1: W_eff, windowed impulse ----------------
__global__ __launch_bounds__(64) void build_Weff(
        const float* __restrict__ wf,   // (8,1,3)
        const float* __restrict__ wr,   // (8,8,8,3)
        float* __restrict__ Weff){      // (512,8)  [p][c]
    int p = blockIdx.x, t = threadIdx.x;
    int c = t >> 3, u = t & 7;          // channel, window slot
    __shared__ float winA[64];
    __shared__ float winB[64];
    __shared__ float taps[256];

    // Prefetch ALL levels' taps into registers up front (single-wave block
    // cannot hide per-level load latency otherwise).
    float tw0[8], tw1[8], tw2[8];
    #pragma unroll
    for (int l = 0; l < 8; l++){
        const float* w = wr + ((l*8 + c)*8 + u)*3;
        tw0[l] = w[0]; tw1[l] = w[1]; tw2[l] = w[2];
    }

    // stage 1: conv(1->8,k3,p1)+pool2 of impulse e_p. Fused 4-tap stride-2
    // conv, taps [w0, w0+w1, w1+w2, w2]*0.5; nonzero only where 2q+j == p.
    int base = (p >> 1) - 1; if (base < 0) base = 0;
    {
        float w0 = wf[c*3+0], w1 = wf[c*3+1], w2 = wf[c*3+2];
        float tap0 = 0.5f*w0, tap1 = 0.5f*(w0+w1), tap2 = 0.5f*(w1+w2), tap3 = 0.5f*w2;
        int q = base + u;
        float v = 0.f;
        if (q < 256){
            int j = p - 2*q;
            if (j == -1) v = tap0;
            else if (j == 0) v = tap1;
            else if (j == 1) v = tap2;
            else if (j == 2) v = tap3;
        }
        winA[c*8+u] = v;
    }
    // NOTE: no LDS-pointer array initializers on gfx950 (addrspacecast in
    // static initializer is rejected) — plain pointer swap.
    float* inw  = winA;
    float* outw = winB;
    int Ln = 256;
    for (int l = 0; l < 8; l++){
        {
            float w0 = tw0[l], w1 = tw1[l], w2 = tw2[l];
            taps[t*4+0] = 0.5f*w0;
            taps[t*4+1] = 0.5f*(w0+w1);
            taps[t*4+2] = 0.5f*(w1+w2);
            taps[t*4+3] = 0.5f*w2;
        }
        __syncthreads();
        int Lo = Ln >> 1;
        int nb = (base - 2) >> 1; if (nb < 0) nb = 0;
        int q = nb + u;
        float acc = 0.f;
        if (q < Lo){
            #pragma unroll
            for (int ci = 0; ci < 8; ci++){
                const float* tp = &taps[(c*8+ci)*4];
                #pragma unroll
                for (int j = -1; j <= 2; j++){
                    int m  = 2*q + j;       // input position (global)
                    int wi = m - base;      // window index
                    float h = (m >= 0 && m < Ln && wi >= 0 && wi < 8)
                              ? inw[ci*8 + wi] : 0.f;
                    acc += tp[j+1] * h;
                }
            }
        }
        outw[c*8+u] = acc;
        float* tmp = inw; inw = outw; outw = tmp;
        base = nb; Ln = Lo;
        __syncthreads();
    }
    // final length 1, base == 0: answer at window slot 0; transposed store
    if (u == 0) Weff[p*8 + c] = inw[c*8 + 0];
}

// ---------- Kernel 2: coalesced hit-decode + per-wave hist + V epilogue ----------
__global__ __launch_bounds__(512) void cnn_main(
        const float* __restrict__ x,     // (512,512,20) f32 one-hot
        const float* __restrict__ Weff,  // (512,8) [p][c]
        const float* __restrict__ lpm,   // (20,20)
        const float* __restrict__ pm,    // (20,20)
        float* __restrict__ out){        // (512,20,8) f32
    int b = blockIdx.x, t = threadIdx.x;
    __shared__ float W[4096];            // [p][c]
    __shared__ float V[400];             // U minus identity (diag 0, col19 0)
    __shared__ float T[8][160];          // per-wave histograms [c*20+i]
    __shared__ float Ts[160];
    // stage Weff with float4 (2 per thread)
    for (int idx = t; idx < 1024; idx += 512)
        ((float4*)W)[idx] = ((const float4*)Weff)[idx];
    // V table once per block
    if (t < 400){
        int i = t / 20, k = t % 20;
        float v = 0.f;
        if (k != 19 && k != i){
            int r  = (k > i) ? i : k;
            int cc = (k > i) ? k : i;
            float l = fminf(fmaxf(lpm[r*20 + cc], 1e-3f), 1.0f);
            v = l * pm[r*20 + cc];
        }
        V[t] = v;
    }
    for (int idx = t; idx < 1280; idx += 512) (&T[0][0])[idx] = 0.f;
    __syncthreads();

    // x block slice = 2560 float4s; row p = g/5 (20 = 5 aligned float4s),
    // local offset (g%5)*4. Fully coalesced: g = t + 512*it. The thread
    // whose float4 holds the row's single 1.0 does that row's atomics.
    const float4* xb4 = (const float4*)(x + (size_t)b * 10240);
    int wid = t >> 6;
    float* Tw = &T[wid][0];
    #pragma unroll
    for (int it = 0; it < 5; it++){
        int g = t + 512*it;
        float4 v = xb4[g];
        int e = -1;
        if (v.x != 0.f) e = 0;
        if (v.y != 0.f) e = 1;
        if (v.z != 0.f) e = 2;
        if (v.w != 0.f) e = 3;
        if (e >= 0){
            int p  = g / 5;
            int aa = (g - 5*p)*4 + e;
            const float4* Wp = (const float4*)&W[p*8];
            float4 w0 = Wp[0], w1 = Wp[1];
            atomicAdd(&Tw[0*20 + aa], w0.x);
            atomicAdd(&Tw[1*20 + aa], w0.y);
            atomicAdd(&Tw[2*20 + aa], w0.z);
            atomicAdd(&Tw[3*20 + aa], w0.w);
            atomicAdd(&Tw[4*20 + aa], w1.x);
            atomicAdd(&Tw[5*20 + aa], w1.y);
            atomicAdd(&Tw[6*20 + aa], w1.z);
            atomicAdd(&Tw[7*20 + aa], w1.w);
        }
    }
    __syncthreads();
    if (t < 160){
        float s = 0.f;
        #pragma unroll
        for (int w = 0; w < 8; w++) s += T[w][t];
        Ts[t] = s;
    }
    __syncthreads();
    if (t < 160){
        int k = t >> 3, c = t & 7;
        float acc = Ts[c*20 + k];              // identity term (U[k,k]=1)
        #pragma unroll
        for (int i = 0; i < 20; i++)
            acc += Ts[c*20 + i] * V[i*20 + k]; // V diag/col19 already 0
        out[(size_t)b*160 + t] = acc;          // out[b][k][c], t = k*8+c
    }
}

extern "C" void kernel_launch(void* const* d_in, const int* in_sizes, int n_in,
                              void* d_out, int out_size, void* d_ws, size_t ws_size,
                              hipStream_t stream){
    const float* x   = (const float*)d_in[0];
    // d_in[1] = masks (unused by forward)
    const float* lpm = (const float*)d_in[2];
    const float* pm  = (const float*)d_in[3];
    const float* wf  = (const float*)d_in[4];
    const float* wr  = (const float*)d_in[5];
    float* Weff = (float*)d_ws;          // 512*8 floats

    hipLaunchKernelGGL(build_Weff, dim3(512), dim3(64),  0, stream, wf, wr, Weff);
    hipLaunchKernelGGL(cnn_main,   dim3(512), dim3(512), 0, stream, x, Weff, lpm, pm,
                       (float*)d_out);
}